// Round 5
// baseline (141.027 us; speedup 1.0000x reference)
//
#include <hip/hip_runtime.h>
#include <hip/hip_bf16.h>

// KAN harmonic-basis GEMM, v5: barrier-free, LDS-free.
// out[b,h] = sum_{d,f} basis(x[b,d])[f] * W[d,f,h] + sum_d b[d,h]
//
// f=0 + bias -> fp32 partials c_part[8][256], summed in GEMM epilogue.
// f=1..10    -> bf16 MFMA GEMM, M=16384, N=256, K=2560.
// Wave tile 64x32 (i=4, j=2). Block = 4 row-stacked waves (BM=256, BN=32);
// grid 64x8 = 512 blocks = 2048 waves = 2 waves/SIMD. NO LDS, NO barriers:
// each lane generates its A-fragment entries directly in MFMA A-operand
// layout from persistent per-dtile sincos state (s1,c1,c2; product formulas
// for harmonics 2..5). B-fragments stream from L2-resident Wfrag
// (fragment-linear, 1.3 MB -> fits each XCD L2) with 1-step register
// prefetch, continuous across dtiles. x prefetched one dtile ahead.

#define HOUT 256
#define DDIM 256
#define NKT  80

typedef __bf16 bf16x8 __attribute__((ext_vector_type(8)));
typedef float floatx4 __attribute__((ext_vector_type(4)));

__device__ __forceinline__ unsigned short f2bf(float f) {
    unsigned int u = __float_as_uint(f);
    return (unsigned short)((u + 0x7FFFu + ((u >> 16) & 1u)) >> 16);
}

__device__ __forceinline__ unsigned int pkbf(float a, float b) {
    __hip_bfloat162 r = __float22bfloat162_rn(make_float2(a, b));
    return *reinterpret_cast<unsigned int*>(&r);
}

// harmonic value for step hs from persistent s1, c1, c2 (hs is compile-time
// constant in the unrolled loop). Order matches W's f = hs+1:
// [s1,c1,s2,c2,s3,c3,s4,c4,s5,c5].
__device__ __forceinline__ float harm(int hs, float s1, float c1, float c2) {
    switch (hs) {
    case 0: return s1;
    case 1: return c1;
    case 2: return (s1 + s1) * c1;                                   // sin2
    case 3: return c2;                                               // cos2
    case 4: return __builtin_fmaf(c2 + c2, s1, s1);                  // sin3
    case 5: return __builtin_fmaf(c2 + c2, c1, -c1);                 // cos3
    case 6: return (c2 + c2) * ((s1 + s1) * c1);                     // sin4 = 2 sin2 cos2
    case 7: return __builtin_fmaf(c2 + c2, c2, -1.f);                // cos4
    case 8: { const float s3 = __builtin_fmaf(c2 + c2, s1, s1);
              return __builtin_fmaf(c2 + c2, s3, -s1); }             // sin5
    case 9: { const float c3 = __builtin_fmaf(c2 + c2, c1, -c1);
              return __builtin_fmaf(c2 + c2, c3, -c1); }             // cos5
    }
    return 0.f;
}

// grid 88 x 256 threads.
// blocks [0,80): kt; Wfrag[kt][n][dd] = bf16(W[(kt/10)*32+dd][kt%10+1][n])
// blocks [80,88): p = bid-80; c_part[p][h] = sum_{d in p*32..+32} W[d][0][h]+b[d][h]
__global__ void prep_kernel(const float* __restrict__ W, const float* __restrict__ bias,
                            unsigned short* __restrict__ Wfrag, float* __restrict__ c_part) {
    const int bid = blockIdx.x;
    const int t = threadIdx.x;
    if (bid < NKT) {
        const int kt = bid;
        const int dtile = kt / 10;
        const int f = kt - dtile * 10 + 1;
        const float* wsrc = W + ((size_t)(dtile * 32) * 11 + f) * 256 + t;
        union { unsigned short s[32]; int4 v[4]; } buf;
#pragma unroll
        for (int dd = 0; dd < 32; ++dd)
            buf.s[dd] = f2bf(wsrc[(size_t)dd * 11 * 256]);
        int4* dst = (int4*)(Wfrag + ((size_t)kt * 256 + t) * 32);
#pragma unroll
        for (int v = 0; v < 4; ++v) dst[v] = buf.v[v];
    } else {
        const int p = bid - NKT;
        float acc = 0.f;
#pragma unroll
        for (int dd = 0; dd < 32; ++dd) {
            const int d = p * 32 + dd;
            acc += W[(size_t)(d * 11) * 256 + t] + bias[(size_t)d * 256 + t];
        }
        c_part[p * 256 + t] = acc;
    }
}

__global__ __launch_bounds__(256, 2)
void kan_gemm(const float* __restrict__ x, const unsigned short* __restrict__ Wfrag,
              const float* __restrict__ c_part, float* __restrict__ out) {
    const int t = threadIdx.x;
    const int lane = t & 63;
    const int wave = t >> 6;
    const int l15 = lane & 15;
    const int koff = lane >> 4;

    const int m0 = blockIdx.x * 256 + wave * 64;   // this wave's 64-row band
    const int n0 = blockIdx.y * 32;                // this block's 32-col band

    // B fragment pointer: frag (kt, jt) at bptr + kt*8192 + jt*512 shorts
    const unsigned short* bptr = Wfrag + (size_t)(n0 + l15) * 32 + koff * 8;

    // x gather base: lane covers rows m0 + it*16 + l15, dd = koff*8 + j
    const float* xbase = x + (size_t)(m0 + l15) * DDIM + koff * 8;

    floatx4 acc[4][2];
#pragma unroll
    for (int it = 0; it < 4; ++it)
#pragma unroll
        for (int jt = 0; jt < 2; ++jt)
            acc[it][jt] = (floatx4){0.f, 0.f, 0.f, 0.f};

    // x for dtile 0
    float4 xq[8];
#pragma unroll
    for (int it = 0; it < 4; ++it) {
        xq[2 * it]     = *(const float4*)(xbase + it * 16 * DDIM);
        xq[2 * it + 1] = *(const float4*)(xbase + it * 16 * DDIM + 4);
    }

    // prime B for kt = 0
    bf16x8 bc[2], bn[2];
    bc[0] = *(const bf16x8*)(bptr);
    bc[1] = *(const bf16x8*)(bptr + 512);

    float s1[4][8], c1[4][8], c2[4][8];

    for (int dtile = 0; dtile < 8; ++dtile) {
        // ---- per-dtile setup: sincos state for 32 x-values ----
#pragma unroll
        for (int it = 0; it < 4; ++it) {
            const float xs[8] = {xq[2 * it].x, xq[2 * it].y, xq[2 * it].z, xq[2 * it].w,
                                 xq[2 * it + 1].x, xq[2 * it + 1].y, xq[2 * it + 1].z, xq[2 * it + 1].w};
#pragma unroll
            for (int jj = 0; jj < 8; ++jj) {
                float s, c;
                __sincosf(xs[jj], &s, &c);
                s1[it][jj] = s;
                c1[it][jj] = c;
                c2[it][jj] = __builtin_fmaf(c + c, c, -1.f);
            }
        }

        // prefetch next dtile's x (in flight during the 10 k-steps below)
        if (dtile < 7) {
            const float* xn = xbase + (dtile + 1) * 32;
#pragma unroll
            for (int it = 0; it < 4; ++it) {
                xq[2 * it]     = *(const float4*)(xn + it * 16 * DDIM);
                xq[2 * it + 1] = *(const float4*)(xn + it * 16 * DDIM + 4);
            }
        }

        const unsigned short* bkt = bptr + (size_t)dtile * 10 * 8192;

#pragma unroll
        for (int hs = 0; hs < 10; ++hs) {
            // prefetch next kt's B frags (continuous across dtiles; the final
            // prefetch reads 8 KB past Wfrag inside d_ws -- harmless, unused)
            bn[0] = *(const bf16x8*)(bkt + (size_t)(hs + 1) * 8192);
            bn[1] = *(const bf16x8*)(bkt + (size_t)(hs + 1) * 8192 + 512);

            // generate A fragments in-register (A-operand layout)
            bf16x8 af[4];
#pragma unroll
            for (int it = 0; it < 4; ++it) {
                union { unsigned int u[4]; bf16x8 v; } a;
#pragma unroll
                for (int p = 0; p < 4; ++p) {
                    const float va = harm(hs, s1[it][2 * p], c1[it][2 * p], c2[it][2 * p]);
                    const float vb = harm(hs, s1[it][2 * p + 1], c1[it][2 * p + 1], c2[it][2 * p + 1]);
                    a.u[p] = pkbf(va, vb);
                }
                af[it] = a.v;
            }

#pragma unroll
            for (int it = 0; it < 4; ++it)
#pragma unroll
                for (int jt = 0; jt < 2; ++jt)
                    acc[it][jt] = __builtin_amdgcn_mfma_f32_16x16x32_bf16(af[it], bc[jt], acc[it][jt], 0, 0, 0);

            bc[0] = bn[0];
            bc[1] = bn[1];
        }
    }

    // ---- epilogue: C/D layout col = lane&15, row = koff*4 + reg ----
    float cj[2];
#pragma unroll
    for (int jt = 0; jt < 2; ++jt) {
        const int col = n0 + jt * 16 + l15;
        float s = 0.f;
#pragma unroll
        for (int p = 0; p < 8; ++p) s += c_part[p * 256 + col];
        cj[jt] = s;
    }
#pragma unroll
    for (int it = 0; it < 4; ++it) {
        const int row0 = m0 + it * 16 + koff * 4;
#pragma unroll
        for (int jt = 0; jt < 2; ++jt) {
            const int col = n0 + jt * 16 + l15;
#pragma unroll
            for (int r = 0; r < 4; ++r)
                out[(size_t)(row0 + r) * HOUT + col] = acc[it][jt][r] + cj[jt];
        }
    }
}

extern "C" void kernel_launch(void* const* d_in, const int* in_sizes, int n_in,
                              void* d_out, int out_size, void* d_ws, size_t ws_size,
                              hipStream_t stream) {
    const float* x = (const float*)d_in[0];
    const float* W = (const float*)d_in[1];
    const float* b = (const float*)d_in[2];
    float* out = (float*)d_out;

    unsigned short* Wfrag = (unsigned short*)d_ws;                      // 1,310,720 B
    float* c_part = (float*)((char*)d_ws + (size_t)NKT * 256 * 32 * 2); // 8 KB

    prep_kernel<<<NKT + 8, 256, 0, stream>>>(W, b, Wfrag, c_part);
    kan_gemm<<<dim3(64, 8), 256, 0, stream>>>(x, Wfrag, c_part, out);
}

// Round 6
// 120.569 us; speedup vs baseline: 1.1697x; 1.1697x over previous
//
#include <hip/hip_runtime.h>
#include <hip/hip_bf16.h>

// KAN harmonic-basis GEMM, v6: barrier-free, LDS-free, spill-free.
// out[b,h] = sum_{d,f} basis(x[b,d])[f] * W[d,f,h] + sum_d b[d,h]
//
// f=0 + bias -> fp32 partials c_part[8][256], summed in GEMM epilogue.
// f=1..10    -> bf16 MFMA GEMM, M=16384, N=256, K=2560.
// Wave tile 32x64 (it=2, jt=4). Block = 4 row-stacked waves (BM=128, BN=64);
// grid 128x4 = 512 blocks = 2048 waves = 2 waves/SIMD. NO LDS, NO barriers:
// each lane generates its A-fragment entries directly in MFMA A-operand
// layout from persistent per-dtile sincos state (s1,c1,c2 for 16 x-values
// = 48 VGPRs; product formulas for harmonics 2..5). B-fragments stream from
// L2-resident Wfrag (fragment-linear, 1.3 MB) with 1-step register prefetch.
// Register budget ~110 arch + 32 acc -> no spills at 2 waves/SIMD (v5 spilled:
// 93 MB scratch writes with it=4's 96-reg state).

#define HOUT 256
#define DDIM 256
#define NKT  80

typedef __bf16 bf16x8 __attribute__((ext_vector_type(8)));
typedef float floatx4 __attribute__((ext_vector_type(4)));

__device__ __forceinline__ unsigned short f2bf(float f) {
    unsigned int u = __float_as_uint(f);
    return (unsigned short)((u + 0x7FFFu + ((u >> 16) & 1u)) >> 16);
}

__device__ __forceinline__ unsigned int pkbf(float a, float b) {
    __hip_bfloat162 r = __float22bfloat162_rn(make_float2(a, b));
    return *reinterpret_cast<unsigned int*>(&r);
}

// harmonic value for step hs from persistent s1, c1, c2 (hs is compile-time
// constant in the unrolled loop). Order matches W's f = hs+1:
// [s1,c1,s2,c2,s3,c3,s4,c4,s5,c5].
__device__ __forceinline__ float harm(int hs, float s1, float c1, float c2) {
    switch (hs) {
    case 0: return s1;
    case 1: return c1;
    case 2: return (s1 + s1) * c1;                                   // sin2
    case 3: return c2;                                               // cos2
    case 4: return __builtin_fmaf(c2 + c2, s1, s1);                  // sin3
    case 5: return __builtin_fmaf(c2 + c2, c1, -c1);                 // cos3
    case 6: return (c2 + c2) * ((s1 + s1) * c1);                     // sin4 = 2 sin2 cos2
    case 7: return __builtin_fmaf(c2 + c2, c2, -1.f);                // cos4
    case 8: { const float s3 = __builtin_fmaf(c2 + c2, s1, s1);
              return __builtin_fmaf(c2 + c2, s3, -s1); }             // sin5
    case 9: { const float c3 = __builtin_fmaf(c2 + c2, c1, -c1);
              return __builtin_fmaf(c2 + c2, c3, -c1); }             // cos5
    }
    return 0.f;
}

// grid 88 x 256 threads.
// blocks [0,80): kt; Wfrag[kt][n][dd] = bf16(W[(kt/10)*32+dd][kt%10+1][n])
// blocks [80,88): p = bid-80; c_part[p][h] = sum_{d in p*32..+32} W[d][0][h]+b[d][h]
__global__ void prep_kernel(const float* __restrict__ W, const float* __restrict__ bias,
                            unsigned short* __restrict__ Wfrag, float* __restrict__ c_part) {
    const int bid = blockIdx.x;
    const int t = threadIdx.x;
    if (bid < NKT) {
        const int kt = bid;
        const int dtile = kt / 10;
        const int f = kt - dtile * 10 + 1;
        const float* wsrc = W + ((size_t)(dtile * 32) * 11 + f) * 256 + t;
        union { unsigned short s[32]; int4 v[4]; } buf;
#pragma unroll
        for (int dd = 0; dd < 32; ++dd)
            buf.s[dd] = f2bf(wsrc[(size_t)dd * 11 * 256]);
        int4* dst = (int4*)(Wfrag + ((size_t)kt * 256 + t) * 32);
#pragma unroll
        for (int v = 0; v < 4; ++v) dst[v] = buf.v[v];
    } else {
        const int p = bid - NKT;
        float acc = 0.f;
#pragma unroll
        for (int dd = 0; dd < 32; ++dd) {
            const int d = p * 32 + dd;
            acc += W[(size_t)(d * 11) * 256 + t] + bias[(size_t)d * 256 + t];
        }
        c_part[p * 256 + t] = acc;
    }
}

__global__ __launch_bounds__(256, 2)
void kan_gemm(const float* __restrict__ x, const unsigned short* __restrict__ Wfrag,
              const float* __restrict__ c_part, float* __restrict__ out) {
    const int t = threadIdx.x;
    const int lane = t & 63;
    const int wave = t >> 6;
    const int l15 = lane & 15;
    const int koff = lane >> 4;

    const int m0 = blockIdx.x * 128 + wave * 32;   // this wave's 32-row band
    const int n0 = blockIdx.y * 64;                // this block's 64-col band

    // B fragment pointer: frag (kt, jt) at bptr + kt*8192 + jt*512 shorts
    const unsigned short* bptr = Wfrag + (size_t)(n0 + l15) * 32 + koff * 8;

    // x gather base: lane covers rows m0 + it*16 + l15, dd = koff*8 + j
    const float* xbase = x + (size_t)(m0 + l15) * DDIM + koff * 8;

    floatx4 acc[2][4];
#pragma unroll
    for (int it = 0; it < 2; ++it)
#pragma unroll
        for (int jt = 0; jt < 4; ++jt)
            acc[it][jt] = (floatx4){0.f, 0.f, 0.f, 0.f};

    // x for dtile 0
    float4 xq[4];
#pragma unroll
    for (int it = 0; it < 2; ++it) {
        xq[2 * it]     = *(const float4*)(xbase + it * 16 * DDIM);
        xq[2 * it + 1] = *(const float4*)(xbase + it * 16 * DDIM + 4);
    }

    // prime B for kt = 0
    bf16x8 bc[4], bn[4];
#pragma unroll
    for (int jt = 0; jt < 4; ++jt)
        bc[jt] = *(const bf16x8*)(bptr + jt * 512);

    float s1[2][8], c1[2][8], c2[2][8];

    for (int dtile = 0; dtile < 8; ++dtile) {
        // ---- per-dtile setup: sincos state for 16 x-values ----
#pragma unroll
        for (int it = 0; it < 2; ++it) {
            const float xs[8] = {xq[2 * it].x, xq[2 * it].y, xq[2 * it].z, xq[2 * it].w,
                                 xq[2 * it + 1].x, xq[2 * it + 1].y, xq[2 * it + 1].z, xq[2 * it + 1].w};
#pragma unroll
            for (int jj = 0; jj < 8; ++jj) {
                float s, c;
                __sincosf(xs[jj], &s, &c);
                s1[it][jj] = s;
                c1[it][jj] = c;
                c2[it][jj] = __builtin_fmaf(c + c, c, -1.f);
            }
        }

        // prefetch next dtile's x (in flight during the 10 k-steps below)
        if (dtile < 7) {
            const float* xn = xbase + (dtile + 1) * 32;
#pragma unroll
            for (int it = 0; it < 2; ++it) {
                xq[2 * it]     = *(const float4*)(xn + it * 16 * DDIM);
                xq[2 * it + 1] = *(const float4*)(xn + it * 16 * DDIM + 4);
            }
        }

        const unsigned short* bkt = bptr + (size_t)dtile * 10 * 8192;

#pragma unroll
        for (int hs = 0; hs < 10; ++hs) {
            // prefetch next kt's B frags (continuous across dtiles; the final
            // prefetch reads 8 KB past Wfrag inside d_ws -- harmless, unused)
#pragma unroll
            for (int jt = 0; jt < 4; ++jt)
                bn[jt] = *(const bf16x8*)(bkt + (size_t)(hs + 1) * 8192 + jt * 512);

            // generate A fragments in-register (A-operand layout)
            bf16x8 af[2];
#pragma unroll
            for (int it = 0; it < 2; ++it) {
                union { unsigned int u[4]; bf16x8 v; } a;
#pragma unroll
                for (int p = 0; p < 4; ++p) {
                    const float va = harm(hs, s1[it][2 * p], c1[it][2 * p], c2[it][2 * p]);
                    const float vb = harm(hs, s1[it][2 * p + 1], c1[it][2 * p + 1], c2[it][2 * p + 1]);
                    a.u[p] = pkbf(va, vb);
                }
                af[it] = a.v;
            }

#pragma unroll
            for (int it = 0; it < 2; ++it)
#pragma unroll
                for (int jt = 0; jt < 4; ++jt)
                    acc[it][jt] = __builtin_amdgcn_mfma_f32_16x16x32_bf16(af[it], bc[jt], acc[it][jt], 0, 0, 0);

#pragma unroll
            for (int jt = 0; jt < 4; ++jt)
                bc[jt] = bn[jt];
        }
    }

    // ---- epilogue: C/D layout col = lane&15, row = koff*4 + reg ----
    float cj[4];
#pragma unroll
    for (int jt = 0; jt < 4; ++jt) {
        const int col = n0 + jt * 16 + l15;
        float s = 0.f;
#pragma unroll
        for (int p = 0; p < 8; ++p) s += c_part[p * 256 + col];
        cj[jt] = s;
    }
#pragma unroll
    for (int it = 0; it < 2; ++it) {
        const int row0 = m0 + it * 16 + koff * 4;
#pragma unroll
        for (int jt = 0; jt < 4; ++jt) {
            const int col = n0 + jt * 16 + l15;
#pragma unroll
            for (int r = 0; r < 4; ++r)
                out[(size_t)(row0 + r) * HOUT + col] = acc[it][jt][r] + cj[jt];
        }
    }
}

extern "C" void kernel_launch(void* const* d_in, const int* in_sizes, int n_in,
                              void* d_out, int out_size, void* d_ws, size_t ws_size,
                              hipStream_t stream) {
    const float* x = (const float*)d_in[0];
    const float* W = (const float*)d_in[1];
    const float* b = (const float*)d_in[2];
    float* out = (float*)d_out;

    unsigned short* Wfrag = (unsigned short*)d_ws;                      // 1,310,720 B
    float* c_part = (float*)((char*)d_ws + (size_t)NKT * 256 * 32 * 2); // 8 KB

    prep_kernel<<<NKT + 8, 256, 0, stream>>>(W, b, Wfrag, c_part);
    kan_gemm<<<dim3(128, 4), 256, 0, stream>>>(x, Wfrag, c_part, out);
}